// Round 8
// baseline (206.620 us; speedup 1.0000x reference)
//
#include <hip/hip_runtime.h>
#include <hip/hip_bf16.h>

// Problem constants (fixed by setup_inputs)
#define BATCH 16
#define NCH 3
#define H 512
#define W 512
#define HW (H * W)          // 262144 = 2^18
#define PAD 7
#define K 26                // int(0.0001 * 512 * 512)
#define NSUB 1024           // sub-chunks (4 rows x 64 cols = 256 px) per batch
#define NPAIR 32            // 2 maps x 16 batches
#define BK (BATCH * K)      // 416
#define CAP 32768           // candidate list capacity per pair
#define LDSCAP 6144         // merge LDS tile (48 KB)

#define ROWS1 46            // tile rows: 32 + 14
#define SHP 68              // padded LDS stride for h-pool rows (64 used)

#define FINF __builtin_inff()

// monotone float->u32 key (order-preserving for all floats)
__device__ __forceinline__ unsigned mkey(float f) {
    unsigned u = __float_as_uint(f);
    unsigned m = (unsigned)(((int)u) >> 31) | 0x80000000u;
    return u ^ m;
}

__device__ __forceinline__ unsigned long long shfl_xor_u64(unsigned long long v, int m) {
    int lo = __shfl_xor((int)(unsigned)(v & 0xFFFFFFFFull), m);
    int hi = __shfl_xor((int)(unsigned)(v >> 32), m);
    return ((unsigned long long)(unsigned)hi << 32) | (unsigned)lo;
}

template <bool MX>
__device__ __forceinline__ float op(float a, float b) { return MX ? fmaxf(a, b) : fminf(a, b); }
template <bool MX>
__device__ __forceinline__ float4 op4(float4 a, float4 b) {
    return make_float4(op<MX>(a.x, b.x), op<MX>(a.y, b.y), op<MX>(a.z, b.z), op<MX>(a.w, b.w));
}

// h-pool stage: 46 rows x 16 col-groups, direct from global with 5 clamped-base
// float4 loads per 4-output group (exact clamp-to-edge; verified r4). One map.
// COPY: also write the raw center float4 to out (tile interior rows).
template <bool MX, bool COPY>
__device__ __forceinline__ void hstage(const float* __restrict__ xp,
                                       float* __restrict__ sH,
                                       float* __restrict__ outp,
                                       int u, int tx0, int ty0) {
    for (int it = u; it < ROWS1 * 16; it += 256) {
        int r = it >> 4;
        int x0 = (it & 15) << 2;
        int gy = ty0 - PAD + r;
        gy = gy < 0 ? 0 : (gy > H - 1 ? H - 1 : gy);
        const float* rowp = xp + (gy << 9);
        int gx0 = tx0 + x0;
        int aB = gx0 - 8; aB = aB < 0 ? 0 : aB;
        int bB = gx0 - 4; bB = bB < 0 ? 0 : bB;
        int dB = gx0 + 4; dB = dB > W - 4 ? W - 4 : dB;
        int eB = gx0 + 8; eB = eB > W - 4 ? W - 4 : eB;
        float4 fA = *(const float4*)(rowp + aB);
        float4 fB = *(const float4*)(rowp + bB);
        float4 fC = *(const float4*)(rowp + gx0);
        float4 fD = *(const float4*)(rowp + dB);
        float4 fE = *(const float4*)(rowp + eB);
        if (COPY && r >= PAD && r < PAD + 32)
            *(float4*)&outp[((ty0 + r - PAD) << 9) + gx0] = fC;
        float4 m4 = op4<MX>(op4<MX>(fB, fC), fD);
        float tm = op<MX>(op<MX>(m4.x, m4.y), op<MX>(m4.z, m4.w));
        *(float4*)&sH[r * SHP + x0] = make_float4(
            op<MX>(tm, op<MX>(fA.y, op<MX>(fA.z, fA.w))),
            op<MX>(tm, op<MX>(fA.z, op<MX>(fA.w, fE.x))),
            op<MX>(tm, op<MX>(fA.w, op<MX>(fE.x, fE.y))),
            op<MX>(tm, op<MX>(fE.x, op<MX>(fE.y, fE.z))));
    }
}

// v-pool of 2 consecutive output rows from 16 LDS rows (14-row shared core)
template <bool MX>
__device__ __forceinline__ void vpool2(const float* __restrict__ sH, int vy, int vx,
                                       float4 o[2]) {
    const float* p0 = sH + vy * SHP + vx;
    float4 t4 = *(const float4*)(p0 + SHP);
#pragma unroll
    for (int j = 2; j <= 14; ++j) t4 = op4<MX>(t4, *(const float4*)(p0 + j * SHP));
    float4 r0 = *(const float4*)(p0);
    float4 r15 = *(const float4*)(p0 + 15 * SHP);
    o[0] = op4<MX>(r0, t4);
    o[1] = op4<MX>(t4, r15);
}

// ---------------------------------------------------------------------------
// K1: selection maps. 64x32 tile, SINGLE 12.5 KB LDS buffer, sequential
// max/min passes per channel -> 8 blocks/CU, grid 2048 = 8*256 exactly one
// round at full 32-wave occupancy. Each thread owns 2 rows x 4 cols.
// Writes dcK/bcK per-pixel key maps + per-sub (4x64) subkeys for screening.
__global__ __launch_bounds__(256, 8) void pool_maps_kernel(
    const float* __restrict__ x, unsigned* __restrict__ dcK,
    unsigned* __restrict__ bcK, unsigned* __restrict__ subkey) {
    __shared__ __align__(16) float sH[ROWS1 * SHP];
    int blk = blockIdx.x;
    int b = blk >> 7;
    int tile = blk & 127;
    int tx0 = (tile & 7) << 6;
    int ty0 = (tile >> 3) << 5;
    int u = threadIdx.x;
    int cg = u & 15;
    int rg = u >> 4;          // 0..15 row-pairs
    int vx = cg << 2;
    int vy = rg << 1;
    float4 amax[2], amin[2];
    amax[0] = amax[1] = make_float4(-FINF, -FINF, -FINF, -FINF);
    amin[0] = amin[1] = make_float4(FINF, FINF, FINF, FINF);

    for (int c = 0; c < NCH; ++c) {
        const float* xp = x + (((size_t)(b * NCH + c)) << 18);
        hstage<true, false>(xp, sH, nullptr, u, tx0, ty0);
        __syncthreads();
        {
            float4 o[2];
            vpool2<true>(sH, vy, vx, o);
            amax[0] = op4<true>(amax[0], o[0]);
            amax[1] = op4<true>(amax[1], o[1]);
        }
        __syncthreads();
        hstage<false, false>(xp, sH, nullptr, u, tx0, ty0);
        __syncthreads();
        {
            float4 o[2];
            vpool2<false>(sH, vy, vx, o);
            amin[0] = op4<false>(amin[0], o[0]);
            amin[1] = op4<false>(amin[1], o[1]);
        }
        __syncthreads();
    }
    // per-pixel key maps
    unsigned gb = ((unsigned)b << 18) + ((ty0 + vy) << 9) + tx0 + vx;
    *(uint4*)&bcK[gb] =
        make_uint4(~mkey(amax[0].x), ~mkey(amax[0].y), ~mkey(amax[0].z), ~mkey(amax[0].w));
    *(uint4*)&bcK[gb + 512] =
        make_uint4(~mkey(amax[1].x), ~mkey(amax[1].y), ~mkey(amax[1].z), ~mkey(amax[1].w));
    *(uint4*)&dcK[gb] =
        make_uint4(mkey(amin[0].x), mkey(amin[0].y), mkey(amin[0].z), mkey(amin[0].w));
    *(uint4*)&dcK[gb + 512] =
        make_uint4(mkey(amin[1].x), mkey(amin[1].y), mkey(amin[1].z), mkey(amin[1].w));
    // per-sub subkeys: dc = max of min-map over sub; bc = min of max-map.
    // sub = 4 rows x 64 cols = lanes [0,32) / [32,64) of each wave.
    float dmx = fmaxf(fmaxf(fmaxf(amin[0].x, amin[0].y), fmaxf(amin[0].z, amin[0].w)),
                      fmaxf(fmaxf(amin[1].x, amin[1].y), fmaxf(amin[1].z, amin[1].w)));
    float bmn = fminf(fminf(fminf(amax[0].x, amax[0].y), fminf(amax[0].z, amax[0].w)),
                      fminf(fminf(amax[1].x, amax[1].y), fminf(amax[1].z, amax[1].w)));
#pragma unroll
    for (int s = 1; s < 32; s <<= 1) {
        dmx = fmaxf(dmx, __shfl_xor(dmx, s));
        bmn = fminf(bmn, __shfl_xor(bmn, s));
    }
    if ((u & 31) == 0) {
        int sr = u >> 5;      // 0..7
        subkey[b * NSUB + tile * 8 + sr] = mkey(dmx);
        subkey[(BATCH + b) * NSUB + tile * 8 + sr] = ~mkey(bmn);
    }
}

// ---------------------------------------------------------------------------
// K2: tau per (map,batch) pair = 26th-largest per-SUB key-max (1024 subs of
// 256 px). Theorem: the 26 largest sub-maxima sit at 26 distinct pixels, all
// >= tau, so {key >= tau} contains the lexicographic top-26.
// One wave per pair; also zeroes the counter for K3.
__global__ __launch_bounds__(64) void tau_kernel(
    const unsigned* __restrict__ subkey, unsigned* __restrict__ tau,
    int* __restrict__ nCand) {
    int pair = blockIdx.x;
    int lane = threadIdx.x;
    const unsigned* sk = subkey + (size_t)pair * NSUB + lane * 16;
    unsigned long long q[16];
#pragma unroll
    for (int j = 0; j < 16; j += 4) {
        uint4 kq = *(const uint4*)&sk[j];
        q[j + 0] = ((unsigned long long)kq.x << 32) | (unsigned)(lane * 16 + j + 0);
        q[j + 1] = ((unsigned long long)kq.y << 32) | (unsigned)(lane * 16 + j + 1);
        q[j + 2] = ((unsigned long long)kq.z << 32) | (unsigned)(lane * 16 + j + 2);
        q[j + 3] = ((unsigned long long)kq.w << 32) | (unsigned)(lane * 16 + j + 3);
    }
    unsigned tv = 0;
    for (int r = 0; r < K; ++r) {
        unsigned long long m0 = q[0] > q[1] ? q[0] : q[1];
        unsigned long long m1 = q[2] > q[3] ? q[2] : q[3];
        unsigned long long m2 = q[4] > q[5] ? q[4] : q[5];
        unsigned long long m3 = q[6] > q[7] ? q[6] : q[7];
        unsigned long long m4 = q[8] > q[9] ? q[8] : q[9];
        unsigned long long m5 = q[10] > q[11] ? q[10] : q[11];
        unsigned long long m6 = q[12] > q[13] ? q[12] : q[13];
        unsigned long long m7 = q[14] > q[15] ? q[14] : q[15];
        m0 = m0 > m1 ? m0 : m1;
        m2 = m2 > m3 ? m2 : m3;
        m4 = m4 > m5 ? m4 : m5;
        m6 = m6 > m7 ? m6 : m7;
        m0 = m0 > m2 ? m0 : m2;
        m4 = m4 > m6 ? m4 : m6;
        unsigned long long m = m0 > m4 ? m0 : m4;
#pragma unroll
        for (int s = 1; s < 64; s <<= 1) {
            unsigned long long o = shfl_xor_u64(m, s);
            m = o > m ? o : m;
        }
        if (r == K - 1) tv = (unsigned)(m >> 32);
#pragma unroll
        for (int j = 0; j < 16; ++j)
            if (q[j] == m) q[j] = 0;
    }
    if (lane == 0) {
        tau[pair] = tv;
        nCand[pair] = 0;
    }
}

// ---------------------------------------------------------------------------
// K3: stream all 8.4M keys ([2][16][HW], dcK||bcK contiguous), append
// (key,idx)-packed u64 for every key >= tau[pair]. ONE atomicAdd per BLOCK
// (ballot masks + popcount prefixes distribute slots). Append order across
// blocks is nondeterministic; top-26 of a set is order-invariant.
__global__ __launch_bounds__(256) void filter_kernel(
    const unsigned* __restrict__ keys, const unsigned* __restrict__ tau,
    int* __restrict__ nCand, unsigned long long* __restrict__ cand) {
    int gid = blockIdx.x * 256 + threadIdx.x;
    int base = gid << 3;                 // 8 keys per thread; block = 2048 keys
    int pair = base >> 18;               // uniform per block
    unsigned tv = tau[pair];
    uint4 k0 = *(const uint4*)(keys + base);
    uint4 k1 = *(const uint4*)(keys + base + 4);
    unsigned kv[8] = {k0.x, k0.y, k0.z, k0.w, k1.x, k1.y, k1.z, k1.w};
    int lane = threadIdx.x & 63, wv = threadIdx.x >> 6;
    unsigned long long msk[8];
    int tot = 0;
#pragma unroll
    for (int j = 0; j < 8; ++j) {
        msk[j] = __ballot(kv[j] >= tv);
        tot += (int)__popcll(msk[j]);
    }
    __shared__ int sW[4];
    __shared__ int sBase;
    if (lane == 0) sW[wv] = tot;
    __syncthreads();
    if (threadIdx.x == 0) {
        int a0 = sW[0], a1 = sW[1], a2 = sW[2], a3 = sW[3];
        int bt = a0 + a1 + a2 + a3;
        sBase = bt ? atomicAdd(&nCand[pair], bt) : 0;
        sW[0] = 0; sW[1] = a0; sW[2] = a0 + a1; sW[3] = a0 + a1 + a2;
    }
    __syncthreads();
    int off = sBase + sW[wv];
    unsigned long long lt = (1ull << lane) - 1ull;
    unsigned long long* cp = cand + (size_t)pair * CAP;
#pragma unroll
    for (int j = 0; j < 8; ++j) {
        if (kv[j] >= tv) {
            int slot = off + (int)__popcll(msk[j] & lt);
            int p = (base + j) & (HW - 1);
            if (slot < CAP)
                cp[slot] = ((unsigned long long)kv[j] << 32) | (unsigned)(0x7FFFFFFF - p);
        }
        off += (int)__popcll(msk[j]);
    }
}

// ---------------------------------------------------------------------------
// K4: per-pair merge of nCand candidates -> global top-26. LDS-tiled with a
// CACHED per-thread slice max: per round only the winner's owner rescans.
// Unique u64s => equality removes exactly one entry.
// map0 (dc): A1 (argmax of per-pixel channel max, first occurrence).
// map1 (bc): the 26 indices for A2.
__global__ __launch_bounds__(256) void merge_kernel(
    const unsigned long long* __restrict__ cand, const int* __restrict__ nCand,
    const float* __restrict__ img, float* __restrict__ A1, int* __restrict__ idx2all) {
    int pair = blockIdx.x;
    int map = pair >> 4, b = pair & 15;
    int t = threadIdx.x;
    int wv = t >> 6, lane = t & 63;
    int n = nCand[pair];
    n = n < CAP ? n : CAP;
    const unsigned long long* cp = cand + (size_t)pair * CAP;
    __shared__ unsigned long long sC[LDSCAP];
    __shared__ unsigned long long sB[4];
    __shared__ unsigned long long sWin[K];
    __shared__ float sM[K];
    int ntile = (n + LDSCAP - 1) / LDSCAP;
    unsigned long long kc = 0;
    for (int tl = 0; tl < ntile; ++tl) {
        int lo = tl * LDSCAP;
        int m = n - lo; m = m > LDSCAP ? LDSCAP : m;
        for (int i = t; i < m; i += 256) sC[i] = cp[lo + i];
        if (tl > 0) kc = (t < K) ? sWin[t] : 0ull;
        __syncthreads();
        unsigned long long lm = 0;
        int slot = -1;
        for (int i = t; i < m; i += 256) {
            unsigned long long v = sC[i];
            if (v > lm) { lm = v; slot = i; }
        }
        for (int r = 0; r < K; ++r) {
            unsigned long long mm = lm > kc ? lm : kc;
#pragma unroll
            for (int s = 1; s < 64; s <<= 1) {
                unsigned long long o = shfl_xor_u64(mm, s);
                mm = o > mm ? o : mm;
            }
            if (lane == 0) sB[wv] = mm;
            __syncthreads();
            unsigned long long wb = sB[0];
            if (sB[1] > wb) wb = sB[1];
            if (sB[2] > wb) wb = sB[2];
            if (sB[3] > wb) wb = sB[3];
            if (t == 0) sWin[r] = wb;
            if (wb == lm) {                 // owner: remove + rescan own slice
                sC[slot] = 0ull;
                lm = 0; slot = -1;
                for (int i = t; i < m; i += 256) {
                    unsigned long long v = sC[i];
                    if (v > lm) { lm = v; slot = i; }
                }
            }
            if (wb == kc) kc = 0ull;
            __syncthreads();
        }
    }
    if (map == 0) {
        if (t < K) {
            int p = 0x7FFFFFFF - (int)(unsigned)(sWin[t] & 0xFFFFFFFFull);
            float m = img[(((size_t)(b * NCH + 0)) << 18) + p];
            m = fmaxf(m, img[(((size_t)(b * NCH + 1)) << 18) + p]);
            m = fmaxf(m, img[(((size_t)(b * NCH + 2)) << 18) + p]);
            sM[t] = m;
        }
        __syncthreads();
        if (t == 0) {
            float bm = -FINF;
            int bj = 0;
            for (int j = 0; j < K; ++j)
                if (sM[j] > bm) { bm = sM[j]; bj = j; }   // strict > = first occurrence
            int p = 0x7FFFFFFF - (int)(unsigned)(sWin[bj] & 0xFFFFFFFFull);
#pragma unroll
            for (int c = 0; c < NCH; ++c)
                A1[b * NCH + c] = img[(((size_t)(b * NCH + c)) << 18) + p];
        }
    } else {
        if (t < K)
            idx2all[b * K + t] = 0x7FFFFFFF - (int)(unsigned)(sWin[t] & 0xFFFFFFFFull);
    }
}

// ---------------------------------------------------------------------------
// K5: A2 (mean over ALL batches' bottom-k indices — faithful to the
// reference's batch-mixing bug), A = 0.75*A1 + 0.25*A2, d = (1 - A) + 1e-6
__global__ __launch_bounds__(256) void compute_A_kernel(
    const float* __restrict__ img, const int* __restrict__ idx2all,
    const float* __restrict__ A1, float* __restrict__ dvec) {
    int b = blockIdx.x;
    __shared__ float ssum[256];
    for (int c = 0; c < NCH; ++c) {
        float s = 0.0f;
        for (int j = threadIdx.x; j < BK; j += 256)
            s += img[(((size_t)(b * NCH + c)) << 18) + idx2all[j]];
        ssum[threadIdx.x] = s;
        __syncthreads();
        for (int st = 128; st > 0; st >>= 1) {
            if (threadIdx.x < st) ssum[threadIdx.x] += ssum[threadIdx.x + st];
            __syncthreads();
        }
        if (threadIdx.x == 0) {
            float A2 = ssum[0] / (float)BK;
            float A = 0.75f * A1[b * NCH + c] + 0.25f * A2;
            dvec[b * NCH + c] = (1.0f - A) + 1e-6f;
        }
        __syncthreads();
    }
}

// ---------------------------------------------------------------------------
// K6: final fused kernel, 64x32 tile at 8 blocks/CU (grid 2048 = 8*256, one
// round). Per channel: h-max stage from L3-warm x (+ x->out copy), v-pool 2
// rows/thread, fold qmin = min_c (1-M_c)*r_c; then t = 1 - 0.95*qmin.
__global__ __launch_bounds__(256, 8) void final_pool_kernel(
    const float* __restrict__ x, const float* __restrict__ dvec,
    float* __restrict__ out) {
    __shared__ __align__(16) float sH[ROWS1 * SHP];
    int blk = blockIdx.x;
    int b = blk >> 7;
    int tile = blk & 127;
    int tx0 = (tile & 7) << 6;
    int ty0 = (tile >> 3) << 5;
    int u = threadIdx.x;
    int vx = (u & 15) << 2;
    int vy = (u >> 4) << 1;
    float4 qmin[2];
    qmin[0] = qmin[1] = make_float4(FINF, FINF, FINF, FINF);

    for (int c = 0; c < NCH; ++c) {
        const float* xp = x + (((size_t)(b * NCH + c)) << 18);
        float* outp = out + (((size_t)(b * 4 + c)) << 18);
        float rc = 1.0f / dvec[b * NCH + c];
        hstage<true, true>(xp, sH, outp, u, tx0, ty0);
        __syncthreads();
        {
            float4 o[2];
            vpool2<true>(sH, vy, vx, o);
            qmin[0].x = fminf(qmin[0].x, fmaf(-o[0].x, rc, rc));
            qmin[0].y = fminf(qmin[0].y, fmaf(-o[0].y, rc, rc));
            qmin[0].z = fminf(qmin[0].z, fmaf(-o[0].z, rc, rc));
            qmin[0].w = fminf(qmin[0].w, fmaf(-o[0].w, rc, rc));
            qmin[1].x = fminf(qmin[1].x, fmaf(-o[1].x, rc, rc));
            qmin[1].y = fminf(qmin[1].y, fmaf(-o[1].y, rc, rc));
            qmin[1].z = fminf(qmin[1].z, fmaf(-o[1].z, rc, rc));
            qmin[1].w = fminf(qmin[1].w, fmaf(-o[1].w, rc, rc));
        }
        __syncthreads();
    }
    float* outp3 = out + (((size_t)(b * 4 + 3)) << 18);
#pragma unroll
    for (int i = 0; i < 2; ++i) {
        float4 tt;
        tt.x = 1.0f - 0.95f * qmin[i].x;
        tt.y = 1.0f - 0.95f * qmin[i].y;
        tt.z = 1.0f - 0.95f * qmin[i].z;
        tt.w = 1.0f - 0.95f * qmin[i].w;
        *(float4*)&outp3[((ty0 + vy + i) << 9) + tx0 + vx] = tt;
    }
}

// ---------------------------------------------------------------------------
extern "C" void kernel_launch(void* const* d_in, const int* in_sizes, int n_in,
                              void* d_out, int out_size, void* d_ws, size_t ws_size,
                              hipStream_t stream) {
    const float* x = (const float*)d_in[0];
    float* out = (float*)d_out;

    const size_t nPix = (size_t)BATCH * HW;      // 4,194,304

    unsigned long long* cand = (unsigned long long*)d_ws;        // 8 MB
    unsigned* dcK = (unsigned*)(cand + (size_t)NPAIR * CAP);     // 16 MB
    unsigned* bcK = dcK + nPix;                                  // 16 MB (contiguous with dcK)
    unsigned* subkey = bcK + nPix;                               // [2][16][1024]
    unsigned* tau = subkey + (size_t)2 * BATCH * NSUB;
    int* nCand = (int*)(tau + NPAIR);
    float* A1 = (float*)(nCand + NPAIR);
    int* idx2all = (int*)(A1 + BATCH * NCH);
    float* dvec = (float*)(idx2all + BK);

    pool_maps_kernel<<<BATCH * 128, 256, 0, stream>>>(x, dcK, bcK, subkey);
    tau_kernel<<<NPAIR, 64, 0, stream>>>(subkey, tau, nCand);
    filter_kernel<<<(int)(2 * nPix / 8 / 256), 256, 0, stream>>>(dcK, tau, nCand, cand);
    merge_kernel<<<NPAIR, 256, 0, stream>>>(cand, nCand, x, A1, idx2all);
    compute_A_kernel<<<BATCH, 256, 0, stream>>>(x, idx2all, A1, dvec);
    final_pool_kernel<<<BATCH * 128, 256, 0, stream>>>(x, dvec, out);
}

// Round 9
// 97.113 us; speedup vs baseline: 2.1276x; 2.1276x over previous
//
#include <hip/hip_runtime.h>
#include <hip/hip_bf16.h>
#include <hip/hip_fp16.h>

// Problem constants (fixed by setup_inputs)
#define BATCH 16
#define NCH 3
#define H 512
#define W 512
#define HW (H * W)          // 262144 = 2^18
#define PAD 7
#define K 26                // int(0.0001 * 512 * 512)
#define NSUB 1024           // sub-chunks (4 rows x 64 cols = 256 px) per batch
#define NPAIR 32            // 2 maps x 16 batches
#define BK (BATCH * K)      // 416
#define CAP 32768           // candidate list capacity per pair
#define LDSCAP 6144         // merge LDS tile (48 KB)

#define TH1 32              // pool tile height
#define ROWS1 46            // TH1 + 14
#define SHP 68              // padded LDS stride for h-pool rows (64 used)

#define FINF __builtin_inff()

// monotone float->u32 key (order-preserving for all floats)
__device__ __forceinline__ unsigned mkey(float f) {
    unsigned u = __float_as_uint(f);
    unsigned m = (unsigned)(((int)u) >> 31) | 0x80000000u;
    return u ^ m;
}

__device__ __forceinline__ unsigned short f2h(float f) {
    __half h = __float2half(f);
    return *reinterpret_cast<unsigned short*>(&h);
}
__device__ __forceinline__ float h2f(unsigned short s) {
    __half h = *reinterpret_cast<__half*>(&s);
    return __half2float(h);
}

__device__ __forceinline__ unsigned long long shfl_xor_u64(unsigned long long v, int m) {
    int lo = __shfl_xor((int)(unsigned)(v & 0xFFFFFFFFull), m);
    int hi = __shfl_xor((int)(unsigned)(v >> 32), m);
    return ((unsigned long long)(unsigned)hi << 32) | (unsigned)lo;
}

template <bool MX>
__device__ __forceinline__ float op(float a, float b) { return MX ? fmaxf(a, b) : fminf(a, b); }
template <bool MX>
__device__ __forceinline__ float4 op4(float4 a, float4 b) {
    return make_float4(op<MX>(a.x, b.x), op<MX>(a.y, b.y), op<MX>(a.z, b.z), op<MX>(a.w, b.w));
}

// v-pool of one map half: 18 LDS rows -> 4 output rows; optional fp16 global
// write of the per-channel window max (for the final t kernel).
template <bool MX, bool WR>
__device__ __forceinline__ void vpool_half(const float* __restrict__ sH, int vy, int vx,
                                           float4 acc[4], unsigned short* __restrict__ vp,
                                           int gbase) {
    const float* p0 = sH + vy * SHP + vx;
    float4 t4 = *(const float4*)(p0 + 3 * SHP);
#pragma unroll
    for (int j = 4; j <= 14; ++j) t4 = op4<MX>(t4, *(const float4*)(p0 + j * SHP));
    float4 a0 = *(const float4*)(p0);
    float4 a1 = *(const float4*)(p0 + SHP);
    float4 a2 = *(const float4*)(p0 + 2 * SHP);
    float4 b15 = *(const float4*)(p0 + 15 * SHP);
    float4 b16 = *(const float4*)(p0 + 16 * SHP);
    float4 b17 = *(const float4*)(p0 + 17 * SHP);
    float4 o0 = op4<MX>(op4<MX>(a0, a1), op4<MX>(a2, t4));
    float4 o1 = op4<MX>(op4<MX>(a1, a2), op4<MX>(t4, b15));
    float4 o2 = op4<MX>(op4<MX>(a2, t4), op4<MX>(b15, b16));
    float4 o3 = op4<MX>(op4<MX>(t4, b15), op4<MX>(b16, b17));
    if (WR) {
        *(ushort4*)&vp[gbase] = make_ushort4(f2h(o0.x), f2h(o0.y), f2h(o0.z), f2h(o0.w));
        *(ushort4*)&vp[gbase + 512] = make_ushort4(f2h(o1.x), f2h(o1.y), f2h(o1.z), f2h(o1.w));
        *(ushort4*)&vp[gbase + 1024] = make_ushort4(f2h(o2.x), f2h(o2.y), f2h(o2.z), f2h(o2.w));
        *(ushort4*)&vp[gbase + 1536] = make_ushort4(f2h(o3.x), f2h(o3.y), f2h(o3.z), f2h(o3.w));
    }
    acc[0] = op4<MX>(acc[0], o0);
    acc[1] = op4<MX>(acc[1], o1);
    acc[2] = op4<MX>(acc[2], o2);
    acc[3] = op4<MX>(acc[3], o3);
}

// ---------------------------------------------------------------------------
// K1 (r4-proven structure): per 64x32 tile, per channel: h-pool straight from
// global (5 clamped-base float4 loads per 4-output group == exact
// clamp-to-edge), max AND min from the same loads into two LDS buffers;
// x->out copy rides on the center float4. v-pool half-split: u<128 -> max map
// (bc keys + fp16 Vmax store), u>=128 -> min map (dc keys). Also emits
// per-sub (4x64) key maxima for screening.
__global__ __launch_bounds__(256, 6) void pool_maps_kernel(
    const float* __restrict__ x, unsigned short* __restrict__ vmaxh,
    unsigned* __restrict__ dcK, unsigned* __restrict__ bcK,
    unsigned* __restrict__ subkey, float* __restrict__ out) {
    __shared__ __align__(16) float sHmax[ROWS1 * SHP];
    __shared__ __align__(16) float sHmin[ROWS1 * SHP];
    int blk = blockIdx.x;
    int b = blk >> 7;
    int tile = blk & 127;
    int tx0 = (tile & 7) << 6;
    int ty0 = (tile >> 3) << 5;
    int u = threadIdx.x;
    int half = u >> 7;      // 0: max map (bc + Vmax), 1: min map (dc)
    int v = u & 127;
    int rg = v >> 4;        // 0..7  (sub-chunk row group)
    int cg = v & 15;
    int vx = cg << 2;
    int vy = rg << 2;
    float4 acc[4];
    float ainit = half ? FINF : -FINF;
#pragma unroll
    for (int i = 0; i < 4; ++i) acc[i] = make_float4(ainit, ainit, ainit, ainit);

    for (int c = 0; c < NCH; ++c) {
        const float* xp = x + (((size_t)(b * NCH + c)) << 18);
        float* outp = out + (((size_t)(b * 4 + c)) << 18);
        for (int it = u; it < ROWS1 * 16; it += 256) {
            int r = it >> 4;
            int x0 = (it & 15) << 2;
            int gy = ty0 - PAD + r;
            gy = gy < 0 ? 0 : (gy > H - 1 ? H - 1 : gy);
            const float* rowp = xp + (gy << 9);
            int gx0 = tx0 + x0;
            int aB = gx0 - 8; aB = aB < 0 ? 0 : aB;
            int bB = gx0 - 4; bB = bB < 0 ? 0 : bB;
            int dB = gx0 + 4; dB = dB > W - 4 ? W - 4 : dB;
            int eB = gx0 + 8; eB = eB > W - 4 ? W - 4 : eB;
            float4 fA = *(const float4*)(rowp + aB);
            float4 fB = *(const float4*)(rowp + bB);
            float4 fC = *(const float4*)(rowp + gx0);
            float4 fD = *(const float4*)(rowp + dB);
            float4 fE = *(const float4*)(rowp + eB);
            if (r >= PAD && r < PAD + TH1)
                *(float4*)&outp[((ty0 + r - PAD) << 9) + gx0] = fC;
            float4 m4 = op4<true>(op4<true>(fB, fC), fD);
            float tmx = fmaxf(fmaxf(m4.x, m4.y), fmaxf(m4.z, m4.w));
            float4 n4 = op4<false>(op4<false>(fB, fC), fD);
            float tmn = fminf(fminf(n4.x, n4.y), fminf(n4.z, n4.w));
            *(float4*)&sHmax[r * SHP + x0] = make_float4(
                fmaxf(tmx, fmaxf(fA.y, fmaxf(fA.z, fA.w))),
                fmaxf(tmx, fmaxf(fA.z, fmaxf(fA.w, fE.x))),
                fmaxf(tmx, fmaxf(fA.w, fmaxf(fE.x, fE.y))),
                fmaxf(tmx, fmaxf(fE.x, fmaxf(fE.y, fE.z))));
            *(float4*)&sHmin[r * SHP + x0] = make_float4(
                fminf(tmn, fminf(fA.y, fminf(fA.z, fA.w))),
                fminf(tmn, fminf(fA.z, fminf(fA.w, fE.x))),
                fminf(tmn, fminf(fA.w, fminf(fE.x, fE.y))),
                fminf(tmn, fminf(fE.x, fminf(fE.y, fE.z))));
        }
        __syncthreads();
        int gbase = ((ty0 + vy) << 9) + tx0 + vx;
        if (half == 0) {
            unsigned short* vp = vmaxh + (((size_t)(b * NCH + c)) << 18);
            vpool_half<true, true>(sHmax, vy, vx, acc, vp, gbase);
        } else {
            vpool_half<false, false>(sHmin, vy, vx, acc, nullptr, 0);
        }
        __syncthreads();
    }
    // ---- per-pixel key maps + per-sub key maxima ----
    unsigned gb = ((unsigned)b << 18) + ((ty0 + vy) << 9) + tx0 + vx;
    if (half == 0) {
        float mn = FINF;
#pragma unroll
        for (int i = 0; i < 4; ++i) {
            float4 o = acc[i];
            *(uint4*)&bcK[gb + (i << 9)] =
                make_uint4(~mkey(o.x), ~mkey(o.y), ~mkey(o.z), ~mkey(o.w));
            mn = fminf(mn, fminf(fminf(o.x, o.y), fminf(o.z, o.w)));
        }
#pragma unroll
        for (int s = 1; s < 16; s <<= 1) mn = fminf(mn, __shfl_xor(mn, s));
        if (cg == 0) subkey[(BATCH + b) * NSUB + tile * 8 + rg] = ~mkey(mn);
    } else {
        float mx = -FINF;
#pragma unroll
        for (int i = 0; i < 4; ++i) {
            float4 o = acc[i];
            *(uint4*)&dcK[gb + (i << 9)] =
                make_uint4(mkey(o.x), mkey(o.y), mkey(o.z), mkey(o.w));
            mx = fmaxf(mx, fmaxf(fmaxf(o.x, o.y), fmaxf(o.z, o.w)));
        }
#pragma unroll
        for (int s = 1; s < 16; s <<= 1) mx = fmaxf(mx, __shfl_xor(mx, s));
        if (cg == 0) subkey[b * NSUB + tile * 8 + rg] = mkey(mx);
    }
}

// ---------------------------------------------------------------------------
// K2: tau per (map,batch) pair = 26th-largest per-SUB key-max (1024 subs of
// 256 px). Theorem: the 26 largest sub-maxima sit at 26 distinct pixels, all
// >= tau, so {key >= tau} contains the lexicographic top-26.
// One wave per pair; also zeroes the counter for K3.
__global__ __launch_bounds__(64) void tau_kernel(
    const unsigned* __restrict__ subkey, unsigned* __restrict__ tau,
    int* __restrict__ nCand) {
    int pair = blockIdx.x;
    int lane = threadIdx.x;
    const unsigned* sk = subkey + (size_t)pair * NSUB + lane * 16;
    unsigned long long q[16];
#pragma unroll
    for (int j = 0; j < 16; j += 4) {
        uint4 kq = *(const uint4*)&sk[j];
        q[j + 0] = ((unsigned long long)kq.x << 32) | (unsigned)(lane * 16 + j + 0);
        q[j + 1] = ((unsigned long long)kq.y << 32) | (unsigned)(lane * 16 + j + 1);
        q[j + 2] = ((unsigned long long)kq.z << 32) | (unsigned)(lane * 16 + j + 2);
        q[j + 3] = ((unsigned long long)kq.w << 32) | (unsigned)(lane * 16 + j + 3);
    }
    unsigned tv = 0;
    for (int r = 0; r < K; ++r) {
        unsigned long long m0 = q[0] > q[1] ? q[0] : q[1];
        unsigned long long m1 = q[2] > q[3] ? q[2] : q[3];
        unsigned long long m2 = q[4] > q[5] ? q[4] : q[5];
        unsigned long long m3 = q[6] > q[7] ? q[6] : q[7];
        unsigned long long m4 = q[8] > q[9] ? q[8] : q[9];
        unsigned long long m5 = q[10] > q[11] ? q[10] : q[11];
        unsigned long long m6 = q[12] > q[13] ? q[12] : q[13];
        unsigned long long m7 = q[14] > q[15] ? q[14] : q[15];
        m0 = m0 > m1 ? m0 : m1;
        m2 = m2 > m3 ? m2 : m3;
        m4 = m4 > m5 ? m4 : m5;
        m6 = m6 > m7 ? m6 : m7;
        m0 = m0 > m2 ? m0 : m2;
        m4 = m4 > m6 ? m4 : m6;
        unsigned long long m = m0 > m4 ? m0 : m4;
#pragma unroll
        for (int s = 1; s < 64; s <<= 1) {
            unsigned long long o = shfl_xor_u64(m, s);
            m = o > m ? o : m;
        }
        if (r == K - 1) tv = (unsigned)(m >> 32);
#pragma unroll
        for (int j = 0; j < 16; ++j)
            if (q[j] == m) q[j] = 0;
    }
    if (lane == 0) {
        tau[pair] = tv;
        nCand[pair] = 0;
    }
}

// ---------------------------------------------------------------------------
// K3: stream all 8.4M keys ([2][16][HW], dcK||bcK contiguous), append
// (key,idx)-packed u64 for every key >= tau[pair]. ONE atomicAdd per BLOCK
// (ballot masks + popcount prefixes distribute slots). Append order across
// blocks is nondeterministic; top-26 of a set is order-invariant.
__global__ __launch_bounds__(256) void filter_kernel(
    const unsigned* __restrict__ keys, const unsigned* __restrict__ tau,
    int* __restrict__ nCand, unsigned long long* __restrict__ cand) {
    int gid = blockIdx.x * 256 + threadIdx.x;
    int base = gid << 3;                 // 8 keys per thread; block = 2048 keys
    int pair = base >> 18;               // uniform per block
    unsigned tv = tau[pair];
    uint4 k0 = *(const uint4*)(keys + base);
    uint4 k1 = *(const uint4*)(keys + base + 4);
    unsigned kv[8] = {k0.x, k0.y, k0.z, k0.w, k1.x, k1.y, k1.z, k1.w};
    int lane = threadIdx.x & 63, wv = threadIdx.x >> 6;
    unsigned long long msk[8];
    int tot = 0;
#pragma unroll
    for (int j = 0; j < 8; ++j) {
        msk[j] = __ballot(kv[j] >= tv);
        tot += (int)__popcll(msk[j]);
    }
    __shared__ int sW[4];
    __shared__ int sBase;
    if (lane == 0) sW[wv] = tot;
    __syncthreads();
    if (threadIdx.x == 0) {
        int a0 = sW[0], a1 = sW[1], a2 = sW[2], a3 = sW[3];
        int bt = a0 + a1 + a2 + a3;
        sBase = bt ? atomicAdd(&nCand[pair], bt) : 0;
        sW[0] = 0; sW[1] = a0; sW[2] = a0 + a1; sW[3] = a0 + a1 + a2;
    }
    __syncthreads();
    int off = sBase + sW[wv];
    unsigned long long lt = (1ull << lane) - 1ull;
    unsigned long long* cp = cand + (size_t)pair * CAP;
#pragma unroll
    for (int j = 0; j < 8; ++j) {
        if (kv[j] >= tv) {
            int slot = off + (int)__popcll(msk[j] & lt);
            int p = (base + j) & (HW - 1);
            if (slot < CAP)
                cp[slot] = ((unsigned long long)kv[j] << 32) | (unsigned)(0x7FFFFFFF - p);
        }
        off += (int)__popcll(msk[j]);
    }
}

// ---------------------------------------------------------------------------
// K4: per-pair merge of nCand candidates -> global top-26. LDS-tiled with a
// CACHED per-thread slice max: per round only the winner's owner rescans.
// Unique u64s => equality removes exactly one entry.
// map0 (dc): A1 (argmax of per-pixel channel max, first occurrence).
// map1 (bc): the 26 indices for A2.
__global__ __launch_bounds__(256) void merge_kernel(
    const unsigned long long* __restrict__ cand, const int* __restrict__ nCand,
    const float* __restrict__ img, float* __restrict__ A1, int* __restrict__ idx2all) {
    int pair = blockIdx.x;
    int map = pair >> 4, b = pair & 15;
    int t = threadIdx.x;
    int wv = t >> 6, lane = t & 63;
    int n = nCand[pair];
    n = n < CAP ? n : CAP;
    const unsigned long long* cp = cand + (size_t)pair * CAP;
    __shared__ unsigned long long sC[LDSCAP];
    __shared__ unsigned long long sB[4];
    __shared__ unsigned long long sWin[K];
    __shared__ float sM[K];
    int ntile = (n + LDSCAP - 1) / LDSCAP;
    unsigned long long kc = 0;
    for (int tl = 0; tl < ntile; ++tl) {
        int lo = tl * LDSCAP;
        int m = n - lo; m = m > LDSCAP ? LDSCAP : m;
        for (int i = t; i < m; i += 256) sC[i] = cp[lo + i];
        if (tl > 0) kc = (t < K) ? sWin[t] : 0ull;
        __syncthreads();
        unsigned long long lm = 0;
        int slot = -1;
        for (int i = t; i < m; i += 256) {
            unsigned long long v = sC[i];
            if (v > lm) { lm = v; slot = i; }
        }
        for (int r = 0; r < K; ++r) {
            unsigned long long mm = lm > kc ? lm : kc;
#pragma unroll
            for (int s = 1; s < 64; s <<= 1) {
                unsigned long long o = shfl_xor_u64(mm, s);
                mm = o > mm ? o : mm;
            }
            if (lane == 0) sB[wv] = mm;
            __syncthreads();
            unsigned long long wb = sB[0];
            if (sB[1] > wb) wb = sB[1];
            if (sB[2] > wb) wb = sB[2];
            if (sB[3] > wb) wb = sB[3];
            if (t == 0) sWin[r] = wb;
            if (wb == lm) {                 // owner: remove + rescan own slice
                sC[slot] = 0ull;
                lm = 0; slot = -1;
                for (int i = t; i < m; i += 256) {
                    unsigned long long v = sC[i];
                    if (v > lm) { lm = v; slot = i; }
                }
            }
            if (wb == kc) kc = 0ull;
            __syncthreads();
        }
    }
    if (map == 0) {
        if (t < K) {
            int p = 0x7FFFFFFF - (int)(unsigned)(sWin[t] & 0xFFFFFFFFull);
            float m = img[(((size_t)(b * NCH + 0)) << 18) + p];
            m = fmaxf(m, img[(((size_t)(b * NCH + 1)) << 18) + p]);
            m = fmaxf(m, img[(((size_t)(b * NCH + 2)) << 18) + p]);
            sM[t] = m;
        }
        __syncthreads();
        if (t == 0) {
            float bm = -FINF;
            int bj = 0;
            for (int j = 0; j < K; ++j)
                if (sM[j] > bm) { bm = sM[j]; bj = j; }   // strict > = first occurrence
            int p = 0x7FFFFFFF - (int)(unsigned)(sWin[bj] & 0xFFFFFFFFull);
#pragma unroll
            for (int c = 0; c < NCH; ++c)
                A1[b * NCH + c] = img[(((size_t)(b * NCH + c)) << 18) + p];
        }
    } else {
        if (t < K)
            idx2all[b * K + t] = 0x7FFFFFFF - (int)(unsigned)(sWin[t] & 0xFFFFFFFFull);
    }
}

// ---------------------------------------------------------------------------
// K5: A2 (mean over ALL batches' bottom-k indices — faithful to the
// reference's batch-mixing bug), A = 0.75*A1 + 0.25*A2, d = (1 - A) + 1e-6
__global__ __launch_bounds__(256) void compute_A_kernel(
    const float* __restrict__ img, const int* __restrict__ idx2all,
    const float* __restrict__ A1, float* __restrict__ dvec) {
    int b = blockIdx.x;
    __shared__ float ssum[256];
    for (int c = 0; c < NCH; ++c) {
        float s = 0.0f;
        for (int j = threadIdx.x; j < BK; j += 256)
            s += img[(((size_t)(b * NCH + c)) << 18) + idx2all[j]];
        ssum[threadIdx.x] = s;
        __syncthreads();
        for (int st = 128; st > 0; st >>= 1) {
            if (threadIdx.x < st) ssum[threadIdx.x] += ssum[threadIdx.x + st];
            __syncthreads();
        }
        if (threadIdx.x == 0) {
            float A2 = ssum[0] / (float)BK;
            float A = 0.75f * A1[b * NCH + c] + 0.25f * A2;
            dvec[b * NCH + c] = (1.0f - A) + 1e-6f;
        }
        __syncthreads();
    }
}

// ---------------------------------------------------------------------------
// K6: t = 1 - 0.95 * min_c (1 - M_c)*r_c, streaming fp16 Vmax (25 MB read,
// 17 MB write). x-channels of out were already written by pool_maps.
__global__ __launch_bounds__(256) void final_t_kernel(
    const unsigned short* __restrict__ vmaxh, const float* __restrict__ dvec,
    float* __restrict__ out) {
    int i4 = (blockIdx.x * 256 + threadIdx.x) << 2;
    int b = i4 >> 18;
    int p = i4 & (HW - 1);
    const unsigned short* vp = vmaxh + (((size_t)(b * NCH)) << 18) + p;
    float r0 = 1.0f / dvec[b * NCH + 0];
    float r1 = 1.0f / dvec[b * NCH + 1];
    float r2 = 1.0f / dvec[b * NCH + 2];
    ushort4 v0 = *(const ushort4*)(vp);
    ushort4 v1 = *(const ushort4*)(vp + (1 << 18));
    ushort4 v2 = *(const ushort4*)(vp + (2 << 18));
    float4 t;
    t.x = 1.0f - 0.95f * fminf(fminf(fmaf(-h2f(v0.x), r0, r0), fmaf(-h2f(v1.x), r1, r1)),
                               fmaf(-h2f(v2.x), r2, r2));
    t.y = 1.0f - 0.95f * fminf(fminf(fmaf(-h2f(v0.y), r0, r0), fmaf(-h2f(v1.y), r1, r1)),
                               fmaf(-h2f(v2.y), r2, r2));
    t.z = 1.0f - 0.95f * fminf(fminf(fmaf(-h2f(v0.z), r0, r0), fmaf(-h2f(v1.z), r1, r1)),
                               fmaf(-h2f(v2.z), r2, r2));
    t.w = 1.0f - 0.95f * fminf(fminf(fmaf(-h2f(v0.w), r0, r0), fmaf(-h2f(v1.w), r1, r1)),
                               fmaf(-h2f(v2.w), r2, r2));
    *(float4*)&out[(((size_t)(b * 4 + 3)) << 18) + p] = t;
}

// ---------------------------------------------------------------------------
extern "C" void kernel_launch(void* const* d_in, const int* in_sizes, int n_in,
                              void* d_out, int out_size, void* d_ws, size_t ws_size,
                              hipStream_t stream) {
    const float* x = (const float*)d_in[0];
    float* out = (float*)d_out;

    const size_t nPix = (size_t)BATCH * HW;      // 4,194,304
    const size_t nCh = (size_t)BATCH * NCH * HW; // 12,582,912

    unsigned long long* cand = (unsigned long long*)d_ws;        // 8 MB
    unsigned* dcK = (unsigned*)(cand + (size_t)NPAIR * CAP);     // 16 MB
    unsigned* bcK = dcK + nPix;                                  // 16 MB (contiguous with dcK)
    unsigned short* vmaxh = (unsigned short*)(bcK + nPix);       // 24 MB fp16
    unsigned* subkey = (unsigned*)(vmaxh + nCh);                 // [2][16][1024]
    unsigned* tau = subkey + (size_t)2 * BATCH * NSUB;
    int* nCand = (int*)(tau + NPAIR);
    float* A1 = (float*)(nCand + NPAIR);
    int* idx2all = (int*)(A1 + BATCH * NCH);
    float* dvec = (float*)(idx2all + BK);

    pool_maps_kernel<<<BATCH * 128, 256, 0, stream>>>(x, vmaxh, dcK, bcK, subkey, out);
    tau_kernel<<<NPAIR, 64, 0, stream>>>(subkey, tau, nCand);
    filter_kernel<<<(int)(2 * nPix / 8 / 256), 256, 0, stream>>>(dcK, tau, nCand, cand);
    merge_kernel<<<NPAIR, 256, 0, stream>>>(cand, nCand, x, A1, idx2all);
    compute_A_kernel<<<BATCH, 256, 0, stream>>>(x, idx2all, A1, dvec);
    final_t_kernel<<<(int)(nPix / 4 / 256), 256, 0, stream>>>(vmaxh, dvec, out);
}